// Round 1
// baseline (393.072 us; speedup 1.0000x reference)
//
#include <hip/hip_runtime.h>
#include <hip/hip_bf16.h>
#include <cstdint>

#define B_SZ   4096
#define F_SZ   30
#define D_SZ   128
#define P_SZ   435
#define BM     64
#define FD     (F_SZ * D_SZ)   // 3840

typedef __bf16 bf16x8 __attribute__((ext_vector_type(8)));
typedef float  f32x4  __attribute__((ext_vector_type(4)));
typedef unsigned short u16x8 __attribute__((ext_vector_type(8)));

__device__ __forceinline__ unsigned short f2bf(float x) {
    // round-to-nearest-even fp32 -> bf16 (finite inputs only)
    unsigned int u = __float_as_uint(x);
    u += 0x7fffu + ((u >> 16) & 1u);
    return (unsigned short)(u >> 16);
}

__global__ __launch_bounds__(256, 3)
void bilinear_kernel(const float* __restrict__ femb,
                     const float* __restrict__ W,
                     float* __restrict__ out) {
    // LDS tiles, bf16, XOR-swizzled: chunk-of-8 index c stored at (c ^ (row&7))
    __shared__ unsigned short As[BM * D_SZ];     // 16 KB  [64][128]
    __shared__ unsigned short Ws[D_SZ * D_SZ];   // 32 KB  [128][128]

    const int bid = blockIdx.x;
    const int p   = bid >> 6;        // pair index (blocks with same p adjacent)
    const int m0  = (bid & 63) * BM; // b-tile start

    // pair p -> (fi, fj) per combinations(range(F),2) ordering
    int fi = 0, rem = p;
    while (rem >= F_SZ - 1 - fi) { rem -= F_SZ - 1 - fi; ++fi; }
    const int fj = fi + 1 + rem;

    const int tid = threadIdx.x;

    // ---- stage A tile (v_i rows), fp32 -> bf16, swizzled ----
    #pragma unroll
    for (int it = 0; it < 4; ++it) {
        int chunk = it * 256 + tid;
        int row = chunk >> 4;
        int c   = chunk & 15;
        const float* src = femb + (size_t)(m0 + row) * FD + fi * D_SZ + c * 8;
        f32x4 f0 = *reinterpret_cast<const f32x4*>(src);
        f32x4 f1 = *reinterpret_cast<const f32x4*>(src + 4);
        u16x8 v;
        v[0]=f2bf(f0[0]); v[1]=f2bf(f0[1]); v[2]=f2bf(f0[2]); v[3]=f2bf(f0[3]);
        v[4]=f2bf(f1[0]); v[5]=f2bf(f1[1]); v[6]=f2bf(f1[2]); v[7]=f2bf(f1[3]);
        *reinterpret_cast<u16x8*>(&As[row * 128 + ((c ^ (row & 7)) * 8)]) = v;
    }
    // ---- stage W_p tile: Ws[e][d] = W[p][e][d], fp32 -> bf16, swizzled ----
    const float* wp = W + (size_t)p * (D_SZ * D_SZ);
    #pragma unroll
    for (int it = 0; it < 8; ++it) {
        int chunk = it * 256 + tid;
        int e = chunk >> 4;
        int c = chunk & 15;
        const float* src = wp + e * D_SZ + c * 8;
        f32x4 f0 = *reinterpret_cast<const f32x4*>(src);
        f32x4 f1 = *reinterpret_cast<const f32x4*>(src + 4);
        u16x8 v;
        v[0]=f2bf(f0[0]); v[1]=f2bf(f0[1]); v[2]=f2bf(f0[2]); v[3]=f2bf(f0[3]);
        v[4]=f2bf(f1[0]); v[5]=f2bf(f1[1]); v[6]=f2bf(f1[2]); v[7]=f2bf(f1[3]);
        *reinterpret_cast<u16x8*>(&Ws[e * 128 + ((c ^ (e & 7)) * 8)]) = v;
    }
    __syncthreads();

    // ---- MFMA: 2x2 wave grid; each wave 32 rows x 64 cols ----
    const int wave = tid >> 6;
    const int lane = tid & 63;
    const int wr = (wave >> 1) * 32;
    const int wc = (wave & 1) * 64;
    const int lr = lane & 15;   // frag row/col within 16
    const int lg = lane >> 4;   // k-group

    bf16x8 afr[2][4];
    #pragma unroll
    for (int m = 0; m < 2; ++m) {
        int row = wr + m * 16 + lr;
        #pragma unroll
        for (int kk = 0; kk < 4; ++kk) {
            int chunk = kk * 4 + lg;
            afr[m][kk] = *reinterpret_cast<const bf16x8*>(
                &As[row * 128 + ((chunk ^ (row & 7)) * 8)]);
        }
    }

    f32x4 acc[2][4];
    #pragma unroll
    for (int m = 0; m < 2; ++m)
        #pragma unroll
        for (int n = 0; n < 4; ++n) acc[m][n] = (f32x4)0.0f;

    #pragma unroll
    for (int n = 0; n < 4; ++n) {
        int e = wc + n * 16 + lr;
        #pragma unroll
        for (int kk = 0; kk < 4; ++kk) {
            int chunk = kk * 4 + lg;
            bf16x8 bfr = *reinterpret_cast<const bf16x8*>(
                &Ws[e * 128 + ((chunk ^ (e & 7)) * 8)]);
            acc[0][n] = __builtin_amdgcn_mfma_f32_16x16x32_bf16(afr[0][kk], bfr, acc[0][n], 0, 0, 0);
            acc[1][n] = __builtin_amdgcn_mfma_f32_16x16x32_bf16(afr[1][kk], bfr, acc[1][n], 0, 0, 0);
        }
    }

    // ---- epilogue: out[b,p,e] = acc * v_j[b,e]  (fp32) ----
    // C/D layout: col = lane&15, row = (lane>>4)*4 + reg   [m89]
    #pragma unroll
    for (int m = 0; m < 2; ++m) {
        int rowbase = m0 + wr + m * 16 + lg * 4;
        #pragma unroll
        for (int n = 0; n < 4; ++n) {
            int e = wc + n * 16 + lr;
            #pragma unroll
            for (int r = 0; r < 4; ++r) {
                int gr = rowbase + r;
                float vj = femb[(size_t)gr * FD + fj * D_SZ + e];
                out[((size_t)gr * P_SZ + p) * D_SZ + e] = acc[m][n][r] * vj;
            }
        }
    }
}

extern "C" void kernel_launch(void* const* d_in, const int* in_sizes, int n_in,
                              void* d_out, int out_size, void* d_ws, size_t ws_size,
                              hipStream_t stream) {
    const float* femb = (const float*)d_in[0];
    const float* W    = (const float*)d_in[1];
    float* out        = (float*)d_out;
    dim3 grid(P_SZ * (B_SZ / BM));   // 435 * 64 = 27840
    dim3 block(256);
    hipLaunchKernelGGL(bilinear_kernel, grid, block, 0, stream, femb, W, out);
}

// Round 2
// 388.834 us; speedup vs baseline: 1.0109x; 1.0109x over previous
//
#include <hip/hip_runtime.h>
#include <hip/hip_bf16.h>
#include <cstdint>

#define B_SZ   4096
#define F_SZ   30
#define D_SZ   128
#define P_SZ   435
#define BM     64
#define FD     (F_SZ * D_SZ)        // 3840
#define FEMB_ELEMS (B_SZ * F_SZ * D_SZ)   // 15,728,640
#define W_ELEMS    (P_SZ * D_SZ * D_SZ)   // 7,127,040
#define GRID_MAIN  (P_SZ * (B_SZ / BM))   // 27840 (multiple of 8)

typedef __bf16 bf16x8 __attribute__((ext_vector_type(8)));
typedef float  f32x4  __attribute__((ext_vector_type(4)));
typedef unsigned short u16x8 __attribute__((ext_vector_type(8)));

__device__ __forceinline__ unsigned short f2bf(float x) {
    unsigned int u = __float_as_uint(x);
    u += 0x7fffu + ((u >> 16) & 1u);
    return (unsigned short)(u >> 16);
}

__device__ __forceinline__ void gl_lds16(const void* g, void* l) {
    __builtin_amdgcn_global_load_lds(
        (const __attribute__((address_space(1))) unsigned int*)g,
        (__attribute__((address_space(3))) unsigned int*)l, 16, 0, 0);
}

// ---- fp32 -> bf16 convert pass (memory-bound, ~25us for both arrays) ----
__global__ __launch_bounds__(256)
void cvt_bf16_kernel(const float* __restrict__ src,
                     unsigned short* __restrict__ dst, int n8) {
    int stride = gridDim.x * blockDim.x;
    for (int i = blockIdx.x * blockDim.x + threadIdx.x; i < n8; i += stride) {
        const float* s = src + (size_t)i * 8;
        f32x4 a = *reinterpret_cast<const f32x4*>(s);
        f32x4 b = *reinterpret_cast<const f32x4*>(s + 4);
        u16x8 v;
        v[0]=f2bf(a[0]); v[1]=f2bf(a[1]); v[2]=f2bf(a[2]); v[3]=f2bf(a[3]);
        v[4]=f2bf(b[0]); v[5]=f2bf(b[1]); v[6]=f2bf(b[2]); v[7]=f2bf(b[3]);
        *reinterpret_cast<u16x8*>(dst + (size_t)i * 8) = v;
    }
}

// ---- main: per (pair, 64-row b-tile): out[b,p,e] = (vi . W[p,e,:]) * vj[b,e] ----
__global__ __launch_bounds__(256, 3)
void bilinear_kernel(const unsigned short* __restrict__ wsA,   // bf16 femb
                     const unsigned short* __restrict__ wsW,   // bf16 W
                     const float* __restrict__ femb,           // fp32 femb (for vj)
                     float* __restrict__ out) {
    __shared__ unsigned short As[BM * D_SZ];     // 16 KB  [64][128] swizzled
    __shared__ unsigned short Ws[D_SZ * D_SZ];   // 32 KB  [128][128] swizzled

    // bijective XCD swizzle (GRID_MAIN % 8 == 0)
    const int orig = blockIdx.x;
    const int bid  = (orig & 7) * (GRID_MAIN / 8) + (orig >> 3);

    const int p  = bid >> 6;
    const int m0 = (bid & 63) * BM;

    int fi = 0, rem = p;
    while (rem >= F_SZ - 1 - fi) { rem -= F_SZ - 1 - fi; ++fi; }
    const int fj = fi + 1 + rem;

    const int tid  = threadIdx.x;
    const int lane = tid & 63;
    const int wave = tid >> 6;
    const int l16  = lane >> 4;   // 0..3
    const int lc   = lane & 15;   // 0..15

    // ---- stage A tile via global_load_lds: linear LDS dest, swizzled global src ----
    {
        const unsigned short* baseA = wsA + (size_t)m0 * FD + fi * D_SZ;
        #pragma unroll
        for (int it = 0; it < 4; ++it) {
            int r0 = wave * 16 + it * 4;       // wave-uniform row group
            int rl = r0 + l16;                 // this lane's row
            int cs = lc ^ (rl & 7);            // pre-swizzled source chunk
            gl_lds16(baseA + (size_t)rl * FD + cs * 8, &As[r0 * 128]);
        }
    }
    // ---- stage W tile ----
    {
        const unsigned short* baseW = wsW + (size_t)p * (D_SZ * D_SZ);
        #pragma unroll
        for (int it = 0; it < 8; ++it) {
            int r0 = wave * 32 + it * 4;
            int rl = r0 + l16;
            int cs = lc ^ (rl & 7);
            gl_lds16(baseW + rl * 128 + cs * 8, &Ws[r0 * 128]);
        }
    }
    __syncthreads();

    // ---- MFMA, swapped operands: D[row=e][col=b] ----
    const int wb = (wave & 1) * 32;    // b-range of this wave (32 rows)
    const int we = (wave >> 1) * 64;   // e-range of this wave (64 cols)

    bf16x8 afr[2][4];
    #pragma unroll
    for (int m = 0; m < 2; ++m) {
        int bl = wb + m * 16 + lc;
        #pragma unroll
        for (int kk = 0; kk < 4; ++kk)
            afr[m][kk] = *reinterpret_cast<const bf16x8*>(
                &As[bl * 128 + (((kk * 4 + l16) ^ (bl & 7)) * 8)]);
    }

    f32x4 acc[4][2];
    #pragma unroll
    for (int n = 0; n < 4; ++n) { acc[n][0] = (f32x4)0.0f; acc[n][1] = (f32x4)0.0f; }

    #pragma unroll
    for (int n = 0; n < 4; ++n) {
        int el = we + n * 16 + lc;
        #pragma unroll
        for (int kk = 0; kk < 4; ++kk) {
            bf16x8 wfr = *reinterpret_cast<const bf16x8*>(
                &Ws[el * 128 + (((kk * 4 + l16) ^ (el & 7)) * 8)]);
            acc[n][0] = __builtin_amdgcn_mfma_f32_16x16x32_bf16(wfr, afr[0][kk], acc[n][0], 0, 0, 0);
            acc[n][1] = __builtin_amdgcn_mfma_f32_16x16x32_bf16(wfr, afr[1][kk], acc[n][1], 0, 0, 0);
        }
    }

    // ---- epilogue: lane holds 4 consecutive e (regs) for one b (lane&15) ----
    #pragma unroll
    for (int m = 0; m < 2; ++m) {
        int b = m0 + wb + m * 16 + lc;
        const float* vjrow = femb + (size_t)b * FD + fj * D_SZ;
        float* orow = out + ((size_t)b * P_SZ + p) * D_SZ;
        #pragma unroll
        for (int n = 0; n < 4; ++n) {
            int e0 = we + n * 16 + l16 * 4;
            f32x4 vj = *reinterpret_cast<const f32x4*>(vjrow + e0);
            f32x4 r;
            r[0] = acc[n][m][0] * vj[0];
            r[1] = acc[n][m][1] * vj[1];
            r[2] = acc[n][m][2] * vj[2];
            r[3] = acc[n][m][3] * vj[3];
            *reinterpret_cast<f32x4*>(orow + e0) = r;
        }
    }
}

extern "C" void kernel_launch(void* const* d_in, const int* in_sizes, int n_in,
                              void* d_out, int out_size, void* d_ws, size_t ws_size,
                              hipStream_t stream) {
    const float* femb = (const float*)d_in[0];
    const float* W    = (const float*)d_in[1];
    float* out        = (float*)d_out;

    unsigned short* wsA = (unsigned short*)d_ws;
    unsigned short* wsW = wsA + FEMB_ELEMS;

    hipLaunchKernelGGL(cvt_bf16_kernel, dim3(2048), dim3(256), 0, stream,
                       femb, wsA, FEMB_ELEMS / 8);
    hipLaunchKernelGGL(cvt_bf16_kernel, dim3(2048), dim3(256), 0, stream,
                       W, wsW, W_ELEMS / 8);
    hipLaunchKernelGGL(bilinear_kernel, dim3(GRID_MAIN), dim3(256), 0, stream,
                       wsA, wsW, femb, out);
}

// Round 3
// 326.695 us; speedup vs baseline: 1.2032x; 1.1902x over previous
//
#include <hip/hip_runtime.h>
#include <hip/hip_bf16.h>
#include <cstdint>

#define B_SZ   4096
#define F_SZ   30
#define D_SZ   128
#define P_SZ   435
#define BM     128
#define GP     4                      // fj per block (A-tile reuse)
#define NG     120                    // sum over fi of ceil((29-fi)/GP)
#define NBT    (B_SZ / BM)            // 32
#define FD     (F_SZ * D_SZ)          // 3840
#define FEMB_ELEMS (B_SZ * F_SZ * D_SZ)
#define W_ELEMS    (P_SZ * D_SZ * D_SZ)
#define GRID_MAIN  (NG * NBT)         // 3840 (multiple of 8)

typedef __bf16 bf16x8 __attribute__((ext_vector_type(8)));
typedef float  f32x4  __attribute__((ext_vector_type(4)));
typedef unsigned short u16x8 __attribute__((ext_vector_type(8)));
typedef unsigned short u16x4 __attribute__((ext_vector_type(4)));

__device__ __forceinline__ unsigned short f2bf(float x) {
    unsigned int u = __float_as_uint(x);
    u += 0x7fffu + ((u >> 16) & 1u);
    return (unsigned short)(u >> 16);
}
__device__ __forceinline__ float bf2f(unsigned short v) {
    return __uint_as_float(((unsigned int)v) << 16);
}
__device__ __forceinline__ void gl_lds16(const void* g, void* l) {
    __builtin_amdgcn_global_load_lds(
        (const __attribute__((address_space(1))) unsigned int*)g,
        (__attribute__((address_space(3))) unsigned int*)l, 16, 0, 0);
}

__global__ __launch_bounds__(256)
void cvt_bf16_kernel(const float* __restrict__ src,
                     unsigned short* __restrict__ dst, int n8) {
    int stride = gridDim.x * blockDim.x;
    for (int i = blockIdx.x * blockDim.x + threadIdx.x; i < n8; i += stride) {
        const float* s = src + (size_t)i * 8;
        f32x4 a = *reinterpret_cast<const f32x4*>(s);
        f32x4 b = *reinterpret_cast<const f32x4*>(s + 4);
        u16x8 v;
        v[0]=f2bf(a[0]); v[1]=f2bf(a[1]); v[2]=f2bf(a[2]); v[3]=f2bf(a[3]);
        v[4]=f2bf(b[0]); v[5]=f2bf(b[1]); v[6]=f2bf(b[2]); v[7]=f2bf(b[3]);
        *reinterpret_cast<u16x8*>(dst + (size_t)i * 8) = v;
    }
}

// block = (b-tile of 128, fi, group of <=4 fj). A staged once, W per fj.
__global__ __launch_bounds__(256, 2)
void bilinear_kernel(const unsigned short* __restrict__ wsA,
                     const unsigned short* __restrict__ wsW,
                     float* __restrict__ out) {
    __shared__ unsigned short As[BM * D_SZ];     // 32 KB
    __shared__ unsigned short Ws[D_SZ * D_SZ];   // 32 KB

    const int orig = blockIdx.x;
    const int bid  = (orig & 7) * (GRID_MAIN / 8) + (orig >> 3);

    const int btile = bid & 31;
    const int m0    = btile * BM;
    int g = bid >> 5;            // 0..NG-1
    int fi = 0;
    for (;;) {
        int ng = (29 - fi + GP - 1) / GP;
        if (g < ng) break;
        g -= ng; ++fi;
    }
    const int fj0    = fi + 1 + g * GP;
    const int fj_end = (fj0 + GP < 30) ? (fj0 + GP) : 30;
    const int pbase  = 29 * fi - (fi * (fi - 1)) / 2 - fi - 1;  // p = pbase + fj

    const int tid  = threadIdx.x;
    const int lane = tid & 63;
    const int wave = tid >> 6;
    const int l16  = lane >> 4;
    const int lc   = lane & 15;

    // ---- stage A (vi slice, rows m0..m0+127, feature fi), swizzled source ----
    {
        const unsigned short* baseA = wsA + (size_t)m0 * FD + fi * D_SZ;
        #pragma unroll
        for (int it = 0; it < 8; ++it) {
            int r0 = wave * 32 + it * 4;
            int rl = r0 + l16;
            int cs = lc ^ (rl & 7);
            gl_lds16(baseA + (size_t)rl * FD + cs * 8, &As[r0 * 128]);
        }
    }
    // ---- stage W for fj0 ----
    {
        const unsigned short* baseW = wsW + (size_t)(pbase + fj0) * (D_SZ * D_SZ);
        #pragma unroll
        for (int it = 0; it < 8; ++it) {
            int r0 = wave * 32 + it * 4;
            int rl = r0 + l16;
            int cs = lc ^ (rl & 7);
            gl_lds16(baseW + rl * 128 + cs * 8, &Ws[r0 * 128]);
        }
    }
    __syncthreads();

    const int wb = (wave & 1) * 64;    // b-range (64) of this wave
    const int we = (wave >> 1) * 64;   // e-range (64) of this wave

    // ---- A fragments: loaded once, reused for all fj ----
    bf16x8 afr[4][4];
    #pragma unroll
    for (int m = 0; m < 4; ++m) {
        int bl = wb + m * 16 + lc;
        #pragma unroll
        for (int kk = 0; kk < 4; ++kk)
            afr[m][kk] = *reinterpret_cast<const bf16x8*>(
                &As[bl * 128 + (((kk * 4 + l16) ^ (bl & 7)) * 8)]);
    }

    for (int fj = fj0;;) {
        const int p = pbase + fj;

        f32x4 acc[4][4];
        #pragma unroll
        for (int n = 0; n < 4; ++n)
            #pragma unroll
            for (int m = 0; m < 4; ++m) acc[n][m] = (f32x4)0.0f;

        #pragma unroll
        for (int n = 0; n < 4; ++n) {
            int el = we + n * 16 + lc;
            #pragma unroll
            for (int kk = 0; kk < 4; ++kk) {
                bf16x8 wfr = *reinterpret_cast<const bf16x8*>(
                    &Ws[el * 128 + (((kk * 4 + l16) ^ (el & 7)) * 8)]);
                #pragma unroll
                for (int m = 0; m < 4; ++m)
                    acc[n][m] = __builtin_amdgcn_mfma_f32_16x16x32_bf16(
                        wfr, afr[m][kk], acc[n][m], 0, 0, 0);
            }
        }

        // ---- epilogue: out[b,p,e] = acc * vj (bf16), non-temporal stores ----
        #pragma unroll
        for (int m = 0; m < 4; ++m) {
            int b = m0 + wb + m * 16 + lc;
            const unsigned short* vjrow = wsA + (size_t)b * FD + fj * D_SZ;
            float* orow = out + ((size_t)b * P_SZ + p) * D_SZ;
            #pragma unroll
            for (int n = 0; n < 4; ++n) {
                int e0 = we + n * 16 + l16 * 4;
                u16x4 vjb = *reinterpret_cast<const u16x4*>(vjrow + e0);
                f32x4 r;
                r[0] = acc[n][m][0] * bf2f(vjb[0]);
                r[1] = acc[n][m][1] * bf2f(vjb[1]);
                r[2] = acc[n][m][2] * bf2f(vjb[2]);
                r[3] = acc[n][m][3] * bf2f(vjb[3]);
                __builtin_nontemporal_store(r, reinterpret_cast<f32x4*>(orow + e0));
            }
        }

        ++fj;
        if (fj >= fj_end) break;

        __syncthreads();   // all waves done reading Ws
        {
            const unsigned short* baseW = wsW + (size_t)(pbase + fj) * (D_SZ * D_SZ);
            #pragma unroll
            for (int it = 0; it < 8; ++it) {
                int r0 = wave * 32 + it * 4;
                int rl = r0 + l16;
                int cs = lc ^ (rl & 7);
                gl_lds16(baseW + rl * 128 + cs * 8, &Ws[r0 * 128]);
            }
        }
        __syncthreads();   // W ready
    }
}

extern "C" void kernel_launch(void* const* d_in, const int* in_sizes, int n_in,
                              void* d_out, int out_size, void* d_ws, size_t ws_size,
                              hipStream_t stream) {
    const float* femb = (const float*)d_in[0];
    const float* W    = (const float*)d_in[1];
    float* out        = (float*)d_out;

    unsigned short* wsA = (unsigned short*)d_ws;
    unsigned short* wsW = wsA + FEMB_ELEMS;

    hipLaunchKernelGGL(cvt_bf16_kernel, dim3(2048), dim3(256), 0, stream,
                       femb, wsA, FEMB_ELEMS / 8);
    hipLaunchKernelGGL(cvt_bf16_kernel, dim3(2048), dim3(256), 0, stream,
                       W, wsW, W_ELEMS / 8);
    hipLaunchKernelGGL(bilinear_kernel, dim3(GRID_MAIN), dim3(256), 0, stream,
                       wsA, wsW, out);
}